// Round 1
// baseline (2436.115 us; speedup 1.0000x reference)
//
#include <hip/hip_runtime.h>
#include <hip/hip_bf16.h>
#include <math.h>

// Problem constants
constexpr int B_ = 4;
constexpr int N_ = 20000;
constexpr int E_ = 320000;
constexpr int H_ = 64;
constexpr int HEADS_ = 4;
constexpr int DH_ = 16;
constexpr int NCH = 64;                       // attention chunks per (b,head)
constexpr int CS = (N_ + NCH - 1) / NCH;      // 313

// Workspace layout (bytes). Requires ~68 MB of ws.
constexpr size_t HB = (size_t)B_ * N_ * H_ * 4;      // 20,480,000
constexpr size_t OFF_H    = 0;
constexpr size_t OFF_A1   = HB;            // tdst, later k
constexpr size_t OFF_A2   = 2 * HB;        // agg, later v
constexpr size_t OFF_CNT  = 3 * HB;                          // B*N ints
constexpr size_t OFF_POS  = OFF_CNT + (size_t)B_ * N_ * 4;   // B*N ints
constexpr size_t OFF_OFFS = OFF_POS + (size_t)B_ * N_ * 4;   // B*(N+1) ints
constexpr size_t OFF_ESRC = OFF_OFFS + ((size_t)B_ * (N_ + 1) * 4 + 64); // B*E ints
constexpr size_t OFF_AVEC = OFF_ESRC + (size_t)B_ * E_ * 4;  // a: B*64 f
constexpr size_t OFF_Q    = OFF_AVEC + 1024;                 // q: B*64 f
constexpr size_t OFF_CTX  = OFF_Q + 1024;                    // ctx: B*64 f
constexpr size_t OFF_WCMB = OFF_CTX + 1024;                  // wcomb: B*64 f
constexpr size_t OFF_FLAG = OFF_WCMB + 1024;                 // int flag
constexpr size_t OFF_PART = OFF_FLAG + 64;                   // 1024*18 f partials

// ---------------- mask dtype detection ----------------
// bool(u8): words look like 0x01000100 -> neither all<=1 nor all f32-ish
// int32:    all words in {0,1}
// float32:  all words in {0, 0x3f800000}
__global__ void k_maskdetect(const unsigned int* __restrict__ m, int* __restrict__ flag) {
    if (blockIdx.x == 0 && threadIdx.x == 0) {
        bool alli = true, allf = true;
        for (int i = 0; i < 256; ++i) {
            unsigned v = m[i];
            alli = alli && (v <= 1u);
            allf = allf && (v == 0u || v == 0x3f800000u);
        }
        *flag = alli ? 1 : (allf ? 2 : 0);
    }
}

// ---------------- h = relu(gn @ w_node + b_node) ----------------
__global__ __launch_bounds__(256) void k_embed(const float* __restrict__ gn,
                                               const float* __restrict__ w,
                                               const float* __restrict__ bias,
                                               float* __restrict__ h) {
    int lane = threadIdx.x & 63;
    float wc[16];
#pragma unroll
    for (int i = 0; i < 16; ++i) wc[i] = w[i * 64 + lane];
    float bb = bias[lane];
    int gw = (blockIdx.x * blockDim.x + threadIdx.x) >> 6;
    int nw = (gridDim.x * blockDim.x) >> 6;
    for (int node = gw; node < B_ * N_; node += nw) {
        const float* r = gn + (size_t)node * 16;
        float acc = bb;
#pragma unroll
        for (int i = 0; i < 16; ++i) acc = fmaf(r[i], wc[i], acc);
        h[(size_t)node * 64 + lane] = fmaxf(acc, 0.f);
    }
}

// ---------------- CSR build ----------------
__global__ void k_count(const int* __restrict__ links, int* __restrict__ cnt) {
    int i = blockIdx.x * blockDim.x + threadIdx.x;
    if (i >= B_ * E_) return;
    int b = i / E_, e = i - b * E_;
    int dst = links[(size_t)b * 2 * E_ + E_ + e];
    atomicAdd(&cnt[b * N_ + dst], 1);
}

__global__ __launch_bounds__(256) void k_scan(const int* __restrict__ cnt,
                                              int* __restrict__ offs,
                                              int* __restrict__ pos) {
    __shared__ int sd[256];
    __shared__ int sbase;
    int b = blockIdx.x, t = threadIdx.x;
    if (t == 0) { sbase = 0; offs[(size_t)b * (N_ + 1)] = 0; }
    __syncthreads();
    for (int base = 0; base < N_; base += 256) {
        int idx = base + t;
        int c = (idx < N_) ? cnt[(size_t)b * N_ + idx] : 0;
        sd[t] = c;
        __syncthreads();
        for (int ofs = 1; ofs < 256; ofs <<= 1) {
            int v = (t >= ofs) ? sd[t - ofs] : 0;
            __syncthreads();
            sd[t] += v;
            __syncthreads();
        }
        int incl = sd[t];
        int run = sbase;
        __syncthreads();
        if (idx < N_) {
            offs[(size_t)b * (N_ + 1) + idx + 1] = run + incl;
            pos[(size_t)b * N_ + idx] = run + incl - c;
        }
        if (t == 255) sbase = run + incl;
        __syncthreads();
    }
}

__global__ void k_fill(const int* __restrict__ links, int* __restrict__ pos,
                       int* __restrict__ esrc) {
    int i = blockIdx.x * blockDim.x + threadIdx.x;
    if (i >= B_ * E_) return;
    int b = i / E_, e = i - b * E_;
    int src = links[(size_t)b * 2 * E_ + e];
    int dst = links[(size_t)b * 2 * E_ + E_ + e];
    int slot = atomicAdd(&pos[b * N_ + dst], 1);
    esrc[(size_t)b * E_ + slot] = src;
}

// ---------------- tdst = W2^T h + msg_b (per node) ----------------
__global__ __launch_bounds__(256) void k_tdst(const float* __restrict__ h,
                                              const float* __restrict__ mw, // msg_w[l]
                                              const float* __restrict__ mb, // msg_b[l]
                                              float* __restrict__ td) {
    int lane = threadIdx.x & 63;
    float w[64];
#pragma unroll
    for (int i = 0; i < 64; ++i) w[i] = mw[(64 + i) * 64 + lane];
    float bb = mb[lane];
    int gw = (blockIdx.x * blockDim.x + threadIdx.x) >> 6;
    int nw = (gridDim.x * blockDim.x) >> 6;
    for (int node = gw; node < B_ * N_; node += nw) {
        float x = h[(size_t)node * 64 + lane];
        float acc = bb;
#pragma unroll
        for (int i = 0; i < 64; ++i) acc = fmaf(__shfl(x, i), w[i], acc);
        td[(size_t)node * 64 + lane] = acc;
    }
}

// ---------------- agg[n] = sum_{e: dst=n} relu(W1^T h_src + tdst[n]) ----------------
__global__ __launch_bounds__(256) void k_edge(const float* __restrict__ h,
                                              const float* __restrict__ td,
                                              const int* __restrict__ offs,
                                              const int* __restrict__ esrc,
                                              const float* __restrict__ mw, // msg_w[l]
                                              float* __restrict__ agg) {
    int lane = threadIdx.x & 63;
    float w1[64];
#pragma unroll
    for (int i = 0; i < 64; ++i) w1[i] = mw[i * 64 + lane];
    int gw = (blockIdx.x * blockDim.x + threadIdx.x) >> 6;
    int nw = (gridDim.x * blockDim.x) >> 6;
    for (int node = gw; node < B_ * N_; node += nw) {
        int b = node / N_;
        int n = node - b * N_;
        int beg = offs[(size_t)b * (N_ + 1) + n];
        int end = offs[(size_t)b * (N_ + 1) + n + 1];
        float tdv = td[(size_t)node * 64 + lane];
        float acc = 0.f;
        if (beg < end) {
            const int* ep = esrc + (size_t)b * E_;
            size_t hb = (size_t)b * N_;
            int s0 = ep[beg];
            float hs_cur = h[(hb + s0) * 64 + lane];
            int s_ahead = (beg + 1 < end) ? ep[beg + 1] : 0;
            for (int p = beg; p < end; ++p) {
                float hs_nxt = 0.f;
                if (p + 1 < end) hs_nxt = h[(hb + s_ahead) * 64 + lane];
                int s2 = (p + 2 < end) ? ep[p + 2] : 0;
                float mm = tdv;
#pragma unroll
                for (int i = 0; i < 64; ++i) mm = fmaf(__shfl(hs_cur, i), w1[i], mm);
                acc += fmaxf(mm, 0.f);
                hs_cur = hs_nxt;
                s_ahead = s2;
            }
        }
        agg[(size_t)node * 64 + lane] = acc;
    }
}

// ---------------- h += relu([h,agg] @ upd_w + upd_b) ----------------
__global__ __launch_bounds__(256) void k_upd(float* __restrict__ h,
                                             const float* __restrict__ agg,
                                             const float* __restrict__ uw, // upd_w[l]
                                             const float* __restrict__ ub) {
    int lane = threadIdx.x & 63;
    float u1[64], u2[64];
#pragma unroll
    for (int i = 0; i < 64; ++i) u1[i] = uw[i * 64 + lane];
#pragma unroll
    for (int i = 0; i < 64; ++i) u2[i] = uw[(64 + i) * 64 + lane];
    float bb = ub[lane];
    int gw = (blockIdx.x * blockDim.x + threadIdx.x) >> 6;
    int nw = (gridDim.x * blockDim.x) >> 6;
    for (int node = gw; node < B_ * N_; node += nw) {
        float x = h[(size_t)node * 64 + lane];
        float y = agg[(size_t)node * 64 + lane];
        float acc = bb;
#pragma unroll
        for (int i = 0; i < 64; ++i) {
            acc = fmaf(__shfl(x, i), u1[i], acc);
            acc = fmaf(__shfl(y, i), u2[i], acc);
        }
        h[(size_t)node * 64 + lane] = x + fmaxf(acc, 0.f);
    }
}

// ---------------- k/v projections ----------------
__global__ __launch_bounds__(256) void k_kv(const float* __restrict__ h,
                                            const float* __restrict__ wk,
                                            const float* __restrict__ bk,
                                            const float* __restrict__ wv,
                                            const float* __restrict__ bv,
                                            float* __restrict__ kb,
                                            float* __restrict__ vb) {
    int lane = threadIdx.x & 63;
    float wkc[64], wvc[64];
#pragma unroll
    for (int i = 0; i < 64; ++i) wkc[i] = wk[i * 64 + lane];
#pragma unroll
    for (int i = 0; i < 64; ++i) wvc[i] = wv[i * 64 + lane];
    float bk0 = bk[lane], bv0 = bv[lane];
    int gw = (blockIdx.x * blockDim.x + threadIdx.x) >> 6;
    int nw = (gridDim.x * blockDim.x) >> 6;
    for (int node = gw; node < B_ * N_; node += nw) {
        float x = h[(size_t)node * 64 + lane];
        float ka = bk0, va = bv0;
#pragma unroll
        for (int i = 0; i < 64; ++i) {
            float xv = __shfl(x, i);
            ka = fmaf(xv, wkc[i], ka);
            va = fmaf(xv, wvc[i], va);
        }
        kb[(size_t)node * 64 + lane] = ka;
        vb[(size_t)node * 64 + lane] = va;
    }
}

// ---------------- a = relu(ad @ w_ad + b_ad); q = a @ wq + bq ----------------
__global__ __launch_bounds__(64) void k_aq(const float* __restrict__ ad,
                                           const float* __restrict__ wad,
                                           const float* __restrict__ bad,
                                           const float* __restrict__ wq,
                                           const float* __restrict__ bq,
                                           float* __restrict__ a_out,
                                           float* __restrict__ q_out) {
    int b = blockIdx.x, t = threadIdx.x;
    __shared__ float sa[64];
    float acc = bad[t];
#pragma unroll
    for (int i = 0; i < 8; ++i) acc = fmaf(ad[b * 8 + i], wad[i * 64 + t], acc);
    float av = fmaxf(acc, 0.f);
    sa[t] = av;
    a_out[b * 64 + t] = av;
    __syncthreads();
    float qa = bq[t];
    for (int i = 0; i < 64; ++i) qa = fmaf(sa[i], wq[i * 64 + t], qa);
    q_out[b * 64 + t] = qa;
}

// ---------------- attention: chunked online softmax partials ----------------
__global__ __launch_bounds__(256) void k_attn(const float* __restrict__ q,
                                              const float* __restrict__ kb,
                                              const float* __restrict__ vb,
                                              float* __restrict__ part) {
    int id = blockIdx.x;
    int ch = id % NCH;
    int bh = id / NCH;
    int b = bh / HEADS_, hd = bh % HEADS_;
    float qv[16];
#pragma unroll
    for (int d = 0; d < 16; ++d) qv[d] = q[b * 64 + hd * 16 + d];
    float m = -1e30f, s = 0.f, c[16];
#pragma unroll
    for (int d = 0; d < 16; ++d) c[d] = 0.f;
    int n0 = ch * CS;
    int n1 = n0 + CS; if (n1 > N_) n1 = N_;
    for (int n = n0 + threadIdx.x; n < n1; n += 256) {
        const float4* kr = (const float4*)(kb + ((size_t)b * N_ + n) * 64 + hd * 16);
        float kk[16];
        ((float4*)kk)[0] = kr[0]; ((float4*)kk)[1] = kr[1];
        ((float4*)kk)[2] = kr[2]; ((float4*)kk)[3] = kr[3];
        float dot = 0.f;
#pragma unroll
        for (int d = 0; d < 16; ++d) dot = fmaf(qv[d], kk[d], dot);
        dot *= 0.25f;  // 1/sqrt(16)
        float nm = fmaxf(m, dot);
        float p = __expf(dot - nm);
        float cor = __expf(m - nm);
        const float4* vr = (const float4*)(vb + ((size_t)b * N_ + n) * 64 + hd * 16);
        float vv[16];
        ((float4*)vv)[0] = vr[0]; ((float4*)vv)[1] = vr[1];
        ((float4*)vv)[2] = vr[2]; ((float4*)vv)[3] = vr[3];
        s = s * cor + p;
#pragma unroll
        for (int d = 0; d < 16; ++d) c[d] = c[d] * cor + p * vv[d];
        m = nm;
    }
    // wave reduce
#pragma unroll
    for (int o = 1; o < 64; o <<= 1) {
        float m2 = __shfl_xor(m, o);
        float s2 = __shfl_xor(s, o);
        float nm = fmaxf(m, m2);
        float w1 = __expf(m - nm), w2 = __expf(m2 - nm);
        s = s * w1 + s2 * w2;
#pragma unroll
        for (int d = 0; d < 16; ++d) {
            float c2 = __shfl_xor(c[d], o);
            c[d] = c[d] * w1 + c2 * w2;
        }
        m = nm;
    }
    __shared__ float red[4][18];
    int wv_ = threadIdx.x >> 6, lane = threadIdx.x & 63;
    if (lane == 0) {
        red[wv_][0] = m; red[wv_][1] = s;
#pragma unroll
        for (int d = 0; d < 16; ++d) red[wv_][2 + d] = c[d];
    }
    __syncthreads();
    if (threadIdx.x == 0) {
        float gm = red[0][0];
        for (int w = 1; w < 4; ++w) gm = fmaxf(gm, red[w][0]);
        float gs = 0.f, gc[16];
#pragma unroll
        for (int d = 0; d < 16; ++d) gc[d] = 0.f;
        for (int w = 0; w < 4; ++w) {
            float ww = __expf(red[w][0] - gm);
            gs += red[w][1] * ww;
#pragma unroll
            for (int d = 0; d < 16; ++d) gc[d] += red[w][2 + d] * ww;
        }
        float* p = part + (size_t)id * 18;
        p[0] = gm; p[1] = gs;
#pragma unroll
        for (int d = 0; d < 16; ++d) p[2 + d] = gc[d];
    }
}

__global__ __launch_bounds__(64) void k_comb(const float* __restrict__ part,
                                             float* __restrict__ ctx) {
    int bh = blockIdx.x, t = threadIdx.x;
    int b = bh / HEADS_, hd = bh % HEADS_;
    const float* p = part + ((size_t)bh * NCH + t) * 18;
    float m = p[0], s = p[1], c[16];
#pragma unroll
    for (int d = 0; d < 16; ++d) c[d] = p[2 + d];
    float gm = m;
#pragma unroll
    for (int o = 1; o < 64; o <<= 1) gm = fmaxf(gm, __shfl_xor(gm, o));
    float w = __expf(m - gm);
    float sw = s * w;
#pragma unroll
    for (int o = 1; o < 64; o <<= 1) sw += __shfl_xor(sw, o);
    float cg[16];
#pragma unroll
    for (int d = 0; d < 16; ++d) {
        float x = c[d] * w;
#pragma unroll
        for (int o = 1; o < 64; o <<= 1) x += __shfl_xor(x, o);
        cg[d] = x;
    }
    if (t == 0) {
#pragma unroll
        for (int d = 0; d < 16; ++d) ctx[b * 64 + hd * 16 + d] = cg[d] / sw;
    }
}

// ---------------- g = LN(a + ctx@wo + bo); wcomb = g/8 + policy_w ----------------
__global__ __launch_bounds__(64) void k_g(const float* __restrict__ a,
                                          const float* __restrict__ ctx,
                                          const float* __restrict__ wo,
                                          const float* __restrict__ bo,
                                          const float* __restrict__ lng,
                                          const float* __restrict__ lnb,
                                          const float* __restrict__ pw,
                                          float* __restrict__ wcomb) {
    int b = blockIdx.x, t = threadIdx.x;
    __shared__ float sc[64];
    sc[t] = ctx[b * 64 + t];
    __syncthreads();
    float o = bo[t];
    for (int i = 0; i < 64; ++i) o = fmaf(sc[i], wo[i * 64 + t], o);
    float y = a[b * 64 + t] + o;
    float mu = y;
#pragma unroll
    for (int oo = 1; oo < 64; oo <<= 1) mu += __shfl_xor(mu, oo);
    mu *= (1.f / 64.f);
    float d = y - mu;
    float var = d * d;
#pragma unroll
    for (int oo = 1; oo < 64; oo <<= 1) var += __shfl_xor(var, oo);
    var *= (1.f / 64.f);
    float g = d * rsqrtf(var + 1e-5f) * lng[t] + lnb[t];
    wcomb[b * 64 + t] = g * 0.125f + pw[t];
}

// ---------------- logits ----------------
__global__ __launch_bounds__(256) void k_final(const float* __restrict__ h,
                                               const float* __restrict__ wcomb,
                                               const float* __restrict__ pb,
                                               const void* __restrict__ mask,
                                               const int* __restrict__ flagp,
                                               float* __restrict__ out) {
    int idx = blockIdx.x * 256 + threadIdx.x;
    if (idx >= B_ * N_) return;
    int b = idx / N_;
    const float4* wr = (const float4*)(wcomb + b * 64);
    const float4* hr = (const float4*)(h + (size_t)idx * 64);
    float acc = pb[0];
#pragma unroll
    for (int i = 0; i < 16; ++i) {
        float4 hv = hr[i], wv = wr[i];
        acc = fmaf(hv.x, wv.x, acc);
        acc = fmaf(hv.y, wv.y, acc);
        acc = fmaf(hv.z, wv.z, acc);
        acc = fmaf(hv.w, wv.w, acc);
    }
    int flag = *flagp;
    bool mv;
    if (flag == 1)      mv = ((const int*)mask)[idx] != 0;
    else if (flag == 2) mv = ((const float*)mask)[idx] != 0.f;
    else                mv = ((const unsigned char*)mask)[idx] != 0;
    out[idx] = mv ? acc : -1.0e9f;
}

extern "C" void kernel_launch(void* const* d_in, const int* in_sizes, int n_in,
                              void* d_out, int out_size, void* d_ws, size_t ws_size,
                              hipStream_t stream) {
    const float* gn   = (const float*)d_in[0];
    const float* ad   = (const float*)d_in[1];
    const float* wnod = (const float*)d_in[2];
    const float* bnod = (const float*)d_in[3];
    const float* msgw = (const float*)d_in[4];
    const float* msgb = (const float*)d_in[5];
    const float* updw = (const float*)d_in[6];
    const float* updb = (const float*)d_in[7];
    const float* wad  = (const float*)d_in[8];
    const float* bad  = (const float*)d_in[9];
    const float* wq   = (const float*)d_in[10];
    const float* bq   = (const float*)d_in[11];
    const float* wk   = (const float*)d_in[12];
    const float* bk   = (const float*)d_in[13];
    const float* wv   = (const float*)d_in[14];
    const float* bv   = (const float*)d_in[15];
    const float* wo   = (const float*)d_in[16];
    const float* bo   = (const float*)d_in[17];
    const float* lng  = (const float*)d_in[18];
    const float* lnb  = (const float*)d_in[19];
    const float* pw   = (const float*)d_in[20];
    const float* pb   = (const float*)d_in[21];
    const int*   links= (const int*)d_in[22];
    const void*  mask = d_in[23];

    char* ws = (char*)d_ws;
    float* h    = (float*)(ws + OFF_H);
    float* bufA = (float*)(ws + OFF_A1);
    float* bufB = (float*)(ws + OFF_A2);
    int*   cnt  = (int*)(ws + OFF_CNT);
    int*   pos  = (int*)(ws + OFF_POS);
    int*   offs = (int*)(ws + OFF_OFFS);
    int*   esrc = (int*)(ws + OFF_ESRC);
    float* avec = (float*)(ws + OFF_AVEC);
    float* qvec = (float*)(ws + OFF_Q);
    float* ctx  = (float*)(ws + OFF_CTX);
    float* wcmb = (float*)(ws + OFF_WCMB);
    int*   flag = (int*)(ws + OFF_FLAG);
    float* part = (float*)(ws + OFF_PART);
    float* out  = (float*)d_out;

    hipMemsetAsync(cnt, 0, (size_t)B_ * N_ * 4, stream);
    k_maskdetect<<<1, 1, 0, stream>>>((const unsigned int*)mask, flag);
    k_embed<<<4096, 256, 0, stream>>>(gn, wnod, bnod, h);
    int eb = (B_ * E_ + 255) / 256;
    k_count<<<eb, 256, 0, stream>>>(links, cnt);
    k_scan<<<B_, 256, 0, stream>>>(cnt, offs, pos);
    k_fill<<<eb, 256, 0, stream>>>(links, pos, esrc);

    for (int l = 0; l < 2; ++l) {
        const float* mwl = msgw + (size_t)l * 128 * 64;
        const float* mbl = msgb + (size_t)l * 64;
        const float* uwl = updw + (size_t)l * 128 * 64;
        const float* ubl = updb + (size_t)l * 64;
        k_tdst<<<4096, 256, 0, stream>>>(h, mwl, mbl, bufA);
        k_edge<<<4096, 256, 0, stream>>>(h, bufA, offs, esrc, mwl, bufB);
        k_upd<<<4096, 256, 0, stream>>>(h, bufB, uwl, ubl);
    }

    k_aq<<<B_, 64, 0, stream>>>(ad, wad, bad, wq, bq, avec, qvec);
    k_kv<<<4096, 256, 0, stream>>>(h, wk, bk, wv, bv, bufA, bufB);
    k_attn<<<B_ * HEADS_ * NCH, 256, 0, stream>>>(qvec, bufA, bufB, part);
    k_comb<<<B_ * HEADS_, 64, 0, stream>>>(part, ctx);
    k_g<<<B_, 64, 0, stream>>>(avec, ctx, wo, bo, lng, lnb, pw, wcmb);
    k_final<<<(B_ * N_ + 255) / 256, 256, 0, stream>>>(h, wcmb, pb, mask, flag, out);
}

// Round 2
// 970.185 us; speedup vs baseline: 2.5110x; 2.5110x over previous
//
#include <hip/hip_runtime.h>
#include <hip/hip_bf16.h>
#include <math.h>

// Problem constants
constexpr int B_ = 4;
constexpr int N_ = 20000;
constexpr int E_ = 320000;
constexpr int HEADS_ = 4;
constexpr int NCH = 64;                       // attention chunks per (b,head)
constexpr int CS = (N_ + NCH - 1) / NCH;      // 313
constexpr int TPB_ = E_ / 16;                 // 20000 edge tiles per batch

typedef __attribute__((ext_vector_type(8))) short short8;   // 8 bf16
typedef __attribute__((ext_vector_type(4))) float f32x4;

// Workspace layout (bytes). ~84 MB.
constexpr size_t HB = (size_t)B_ * N_ * 64 * 4;      // 20,480,000
constexpr size_t OFF_H    = 0;
constexpr size_t OFF_A1   = HB;            // tdst, later k
constexpr size_t OFF_A2   = 2 * HB;        // agg, later v
constexpr size_t OFF_CNT  = 3 * HB;                          // B*N ints
constexpr size_t OFF_POS  = OFF_CNT + (size_t)B_ * N_ * 4;   // B*N ints
constexpr size_t OFF_OFFS = OFF_POS + (size_t)B_ * N_ * 4;   // B*(N+1) ints
constexpr size_t OFF_ESRC = OFF_OFFS + ((size_t)B_ * (N_ + 1) * 4 + 64); // B*E ints
constexpr size_t OFF_EDST = OFF_ESRC + (size_t)B_ * E_ * 4;  // B*E ints
constexpr size_t OFF_HB16 = OFF_EDST + (size_t)B_ * E_ * 4;  // B*N*64 bf16
constexpr size_t OFF_AVEC = OFF_HB16 + (size_t)B_ * N_ * 64 * 2;
constexpr size_t OFF_Q    = OFF_AVEC + 1024;
constexpr size_t OFF_CTX  = OFF_Q + 1024;
constexpr size_t OFF_WCMB = OFF_CTX + 1024;
constexpr size_t OFF_FLAG = OFF_WCMB + 1024;
constexpr size_t OFF_PART = OFF_FLAG + 64;                   // 1024*18 f partials

static __device__ __forceinline__ unsigned short f2bf(float f) {
    union { float f; unsigned u; } v; v.f = f;
    unsigned r = v.u + 0x7fffu + ((v.u >> 16) & 1u);
    return (unsigned short)(r >> 16);
}

// ---------------- mask dtype detection ----------------
__global__ void k_maskdetect(const unsigned int* __restrict__ m, int* __restrict__ flag) {
    if (blockIdx.x == 0 && threadIdx.x == 0) {
        bool alli = true, allf = true;
        for (int i = 0; i < 256; ++i) {
            unsigned v = m[i];
            alli = alli && (v <= 1u);
            allf = allf && (v == 0u || v == 0x3f800000u);
        }
        *flag = alli ? 1 : (allf ? 2 : 0);
    }
}

// ---------------- h = relu(gn @ w_node + b_node) ----------------
__global__ __launch_bounds__(256) void k_embed(const float* __restrict__ gn,
                                               const float* __restrict__ w,
                                               const float* __restrict__ bias,
                                               float* __restrict__ h) {
    int lane = threadIdx.x & 63;
    float wc[16];
#pragma unroll
    for (int i = 0; i < 16; ++i) wc[i] = w[i * 64 + lane];
    float bb = bias[lane];
    int gw = (blockIdx.x * blockDim.x + threadIdx.x) >> 6;
    int nw = (gridDim.x * blockDim.x) >> 6;
    for (int node = gw; node < B_ * N_; node += nw) {
        const float* r = gn + (size_t)node * 16;
        float a0 = 0.f, a1 = 0.f, a2 = 0.f, a3 = 0.f;
#pragma unroll
        for (int i = 0; i < 16; i += 4) {
            a0 = fmaf(r[i + 0], wc[i + 0], a0);
            a1 = fmaf(r[i + 1], wc[i + 1], a1);
            a2 = fmaf(r[i + 2], wc[i + 2], a2);
            a3 = fmaf(r[i + 3], wc[i + 3], a3);
        }
        h[(size_t)node * 64 + lane] = fmaxf(bb + ((a0 + a1) + (a2 + a3)), 0.f);
    }
}

// ---------------- CSR build ----------------
__global__ void k_count(const int* __restrict__ links, int* __restrict__ cnt) {
    int i = blockIdx.x * blockDim.x + threadIdx.x;
    if (i >= B_ * E_) return;
    int b = i / E_, e = i - b * E_;
    int dst = links[(size_t)b * 2 * E_ + E_ + e];
    atomicAdd(&cnt[b * N_ + dst], 1);
}

__global__ __launch_bounds__(256) void k_scan(const int* __restrict__ cnt,
                                              int* __restrict__ offs,
                                              int* __restrict__ pos) {
    __shared__ int sd[256];
    __shared__ int sbase;
    int b = blockIdx.x, t = threadIdx.x;
    if (t == 0) { sbase = 0; offs[(size_t)b * (N_ + 1)] = 0; }
    __syncthreads();
    for (int base = 0; base < N_; base += 256) {
        int idx = base + t;
        int c = (idx < N_) ? cnt[(size_t)b * N_ + idx] : 0;
        sd[t] = c;
        __syncthreads();
        for (int ofs = 1; ofs < 256; ofs <<= 1) {
            int v = (t >= ofs) ? sd[t - ofs] : 0;
            __syncthreads();
            sd[t] += v;
            __syncthreads();
        }
        int incl = sd[t];
        int run = sbase;
        __syncthreads();
        if (idx < N_) {
            offs[(size_t)b * (N_ + 1) + idx + 1] = run + incl;
            pos[(size_t)b * N_ + idx] = run + incl - c;
        }
        if (t == 255) sbase = run + incl;
        __syncthreads();
    }
}

__global__ void k_fill(const int* __restrict__ links, int* __restrict__ pos,
                       int* __restrict__ esrc, int* __restrict__ edst) {
    int i = blockIdx.x * blockDim.x + threadIdx.x;
    if (i >= B_ * E_) return;
    int b = i / E_, e = i - b * E_;
    int src = links[(size_t)b * 2 * E_ + e];
    int dst = links[(size_t)b * 2 * E_ + E_ + e];
    int slot = atomicAdd(&pos[b * N_ + dst], 1);
    esrc[(size_t)b * E_ + slot] = src;
    edst[(size_t)b * E_ + slot] = dst;
}

// ---------------- tdst = W2^T h + msg_b (per node); also hb16 = bf16(h) ----------------
__global__ __launch_bounds__(256) void k_tdst(const float* __restrict__ h,
                                              const float* __restrict__ mw, // msg_w[l]
                                              const float* __restrict__ mb, // msg_b[l]
                                              float* __restrict__ td,
                                              unsigned short* __restrict__ hb16) {
    int lane = threadIdx.x & 63;
    float w[64];
#pragma unroll
    for (int i = 0; i < 64; ++i) w[i] = mw[(64 + i) * 64 + lane];
    float bb = mb[lane];
    int gw = (blockIdx.x * blockDim.x + threadIdx.x) >> 6;
    int nw = (gridDim.x * blockDim.x) >> 6;
    for (int node = gw; node < B_ * N_; node += nw) {
        float x = h[(size_t)node * 64 + lane];
        hb16[(size_t)node * 64 + lane] = f2bf(x);
        float a0 = 0.f, a1 = 0.f, a2 = 0.f, a3 = 0.f;
#pragma unroll
        for (int i = 0; i < 64; i += 4) {
            a0 = fmaf(__shfl(x, i + 0), w[i + 0], a0);
            a1 = fmaf(__shfl(x, i + 1), w[i + 1], a1);
            a2 = fmaf(__shfl(x, i + 2), w[i + 2], a2);
            a3 = fmaf(__shfl(x, i + 3), w[i + 3], a3);
        }
        td[(size_t)node * 64 + lane] = bb + ((a0 + a1) + (a2 + a3));
    }
}

// ---------------- fused MFMA edge kernel ----------------
// agg[n] += relu(hb16[src] @ W1 + tdst[n]) summed over CSR edges, 16 edges/wave.
__global__ __launch_bounds__(256) void k_edge_mfma(const unsigned short* __restrict__ hb16,
                                                   const float* __restrict__ td,
                                                   const int* __restrict__ esrc,
                                                   const int* __restrict__ edst,
                                                   const float* __restrict__ mw, // msg_w[l]
                                                   float* __restrict__ agg) {
    int lane = threadIdx.x & 63;
    int g = lane >> 4, c = lane & 15;
    int wgl = blockIdx.x * 4 + (threadIdx.x >> 6);   // 0 .. B*TPB-1
    int b = wgl / TPB_;
    int t0 = wgl - b * TPB_;
    int s0 = t0 * 16;
    const int* ep = esrc + (size_t)b * E_;
    const int* dp = edst + (size_t)b * E_;

    // B fragments: W1[k][o], lane: col o = nt*16 + c, k = ks*32 + g*8 + j
    short8 bf[4][2];
#pragma unroll
    for (int nt = 0; nt < 4; ++nt)
#pragma unroll
        for (int ks = 0; ks < 2; ++ks)
#pragma unroll
            for (int j = 0; j < 8; ++j)
                bf[nt][ks][j] = (short)f2bf(mw[(ks * 32 + g * 8 + j) * 64 + nt * 16 + c]);

    // A fragments: rows = 16 CSR slots, lane row = c, k-slice = ks*32 + g*8
    int src = ep[s0 + c];
    const unsigned short* hrow = hb16 + ((size_t)(b * N_) + src) * 64;
    short8 a0 = *(const short8*)(hrow + g * 8);
    short8 a1 = *(const short8*)(hrow + 32 + g * 8);

    f32x4 zero = {0.f, 0.f, 0.f, 0.f};
    f32x4 acc[4];
#pragma unroll
    for (int nt = 0; nt < 4; ++nt) {
        acc[nt] = __builtin_amdgcn_mfma_f32_16x16x32_bf16(a0, bf[nt][0], zero, 0, 0, 0);
        acc[nt] = __builtin_amdgcn_mfma_f32_16x16x32_bf16(a1, bf[nt][1], acc[nt], 0, 0, 0);
    }

    // epilogue: rows owned by this lane are 4g+r; add tdst[dst], relu
    int myd[4];
#pragma unroll
    for (int r = 0; r < 4; ++r) myd[r] = dp[s0 + 4 * g + r];
    float val[4][4]; // [nt][r]
#pragma unroll
    for (int r = 0; r < 4; ++r) {
        const float* trow = td + ((size_t)(b * N_) + myd[r]) * 64;
#pragma unroll
        for (int nt = 0; nt < 4; ++nt)
            val[nt][r] = fmaxf(acc[nt][r] + trow[nt * 16 + c], 0.f);
    }

    // segmented reduce over the 16 CSR-sorted rows
    int i = 0;
    while (i < 16) {
        int d = dp[s0 + i];
        int j = i + 1;
        while (j < 16 && dp[s0 + j] == d) ++j;
        float s0v = 0.f, s1v = 0.f, s2v = 0.f, s3v = 0.f;
#pragma unroll
        for (int r = 0; r < 4; ++r) {
            int rr = 4 * g + r;
            bool in = (rr >= i) && (rr < j);
            s0v += in ? val[0][r] : 0.f;
            s1v += in ? val[1][r] : 0.f;
            s2v += in ? val[2][r] : 0.f;
            s3v += in ? val[3][r] : 0.f;
        }
        s0v += __shfl_xor(s0v, 16); s0v += __shfl_xor(s0v, 32);
        s1v += __shfl_xor(s1v, 16); s1v += __shfl_xor(s1v, 32);
        s2v += __shfl_xor(s2v, 16); s2v += __shfl_xor(s2v, 32);
        s3v += __shfl_xor(s3v, 16); s3v += __shfl_xor(s3v, 32);
        float outv = (g == 0) ? s0v : (g == 1) ? s1v : (g == 2) ? s2v : s3v;
        atomicAdd(&agg[((size_t)(b * N_) + d) * 64 + g * 16 + c], outv);
        i = j;
    }
}

// ---------------- h += relu([h,agg] @ upd_w + upd_b) ----------------
__global__ __launch_bounds__(256) void k_upd(float* __restrict__ h,
                                             const float* __restrict__ agg,
                                             const float* __restrict__ uw,
                                             const float* __restrict__ ub) {
    int lane = threadIdx.x & 63;
    float u1[64], u2[64];
#pragma unroll
    for (int i = 0; i < 64; ++i) u1[i] = uw[i * 64 + lane];
#pragma unroll
    for (int i = 0; i < 64; ++i) u2[i] = uw[(64 + i) * 64 + lane];
    float bb = ub[lane];
    int gw = (blockIdx.x * blockDim.x + threadIdx.x) >> 6;
    int nw = (gridDim.x * blockDim.x) >> 6;
    for (int node = gw; node < B_ * N_; node += nw) {
        float x = h[(size_t)node * 64 + lane];
        float y = agg[(size_t)node * 64 + lane];
        float a0 = 0.f, a1 = 0.f, a2 = 0.f, a3 = 0.f;
#pragma unroll
        for (int i = 0; i < 64; i += 2) {
            a0 = fmaf(__shfl(x, i + 0), u1[i + 0], a0);
            a1 = fmaf(__shfl(y, i + 0), u2[i + 0], a1);
            a2 = fmaf(__shfl(x, i + 1), u1[i + 1], a2);
            a3 = fmaf(__shfl(y, i + 1), u2[i + 1], a3);
        }
        h[(size_t)node * 64 + lane] = x + fmaxf(bb + ((a0 + a1) + (a2 + a3)), 0.f);
    }
}

// ---------------- k/v projections ----------------
__global__ __launch_bounds__(256) void k_kv(const float* __restrict__ h,
                                            const float* __restrict__ wk,
                                            const float* __restrict__ bk,
                                            const float* __restrict__ wv,
                                            const float* __restrict__ bv,
                                            float* __restrict__ kb,
                                            float* __restrict__ vb) {
    int lane = threadIdx.x & 63;
    float wkc[64], wvc[64];
#pragma unroll
    for (int i = 0; i < 64; ++i) wkc[i] = wk[i * 64 + lane];
#pragma unroll
    for (int i = 0; i < 64; ++i) wvc[i] = wv[i * 64 + lane];
    float bk0 = bk[lane], bv0 = bv[lane];
    int gw = (blockIdx.x * blockDim.x + threadIdx.x) >> 6;
    int nw = (gridDim.x * blockDim.x) >> 6;
    for (int node = gw; node < B_ * N_; node += nw) {
        float x = h[(size_t)node * 64 + lane];
        float k0 = 0.f, k1 = 0.f, v0 = 0.f, v1 = 0.f;
#pragma unroll
        for (int i = 0; i < 64; i += 2) {
            float xa = __shfl(x, i + 0);
            float xb = __shfl(x, i + 1);
            k0 = fmaf(xa, wkc[i + 0], k0);
            v0 = fmaf(xa, wvc[i + 0], v0);
            k1 = fmaf(xb, wkc[i + 1], k1);
            v1 = fmaf(xb, wvc[i + 1], v1);
        }
        kb[(size_t)node * 64 + lane] = bk0 + k0 + k1;
        vb[(size_t)node * 64 + lane] = bv0 + v0 + v1;
    }
}

// ---------------- a = relu(ad @ w_ad + b_ad); q = a @ wq + bq ----------------
__global__ __launch_bounds__(64) void k_aq(const float* __restrict__ ad,
                                           const float* __restrict__ wad,
                                           const float* __restrict__ bad,
                                           const float* __restrict__ wq,
                                           const float* __restrict__ bq,
                                           float* __restrict__ a_out,
                                           float* __restrict__ q_out) {
    int b = blockIdx.x, t = threadIdx.x;
    __shared__ float sa[64];
    float acc = bad[t];
#pragma unroll
    for (int i = 0; i < 8; ++i) acc = fmaf(ad[b * 8 + i], wad[i * 64 + t], acc);
    float av = fmaxf(acc, 0.f);
    sa[t] = av;
    a_out[b * 64 + t] = av;
    __syncthreads();
    float qa = bq[t];
    for (int i = 0; i < 64; ++i) qa = fmaf(sa[i], wq[i * 64 + t], qa);
    q_out[b * 64 + t] = qa;
}

// ---------------- attention: chunked online softmax partials ----------------
__global__ __launch_bounds__(256) void k_attn(const float* __restrict__ q,
                                              const float* __restrict__ kb,
                                              const float* __restrict__ vb,
                                              float* __restrict__ part) {
    int id = blockIdx.x;
    int ch = id % NCH;
    int bh = id / NCH;
    int b = bh / HEADS_, hd = bh % HEADS_;
    float qv[16];
#pragma unroll
    for (int d = 0; d < 16; ++d) qv[d] = q[b * 64 + hd * 16 + d];
    float m = -1e30f, s = 0.f, c[16];
#pragma unroll
    for (int d = 0; d < 16; ++d) c[d] = 0.f;
    int n0 = ch * CS;
    int n1 = n0 + CS; if (n1 > N_) n1 = N_;
    for (int n = n0 + threadIdx.x; n < n1; n += 256) {
        const float4* kr = (const float4*)(kb + ((size_t)b * N_ + n) * 64 + hd * 16);
        float kk[16];
        ((float4*)kk)[0] = kr[0]; ((float4*)kk)[1] = kr[1];
        ((float4*)kk)[2] = kr[2]; ((float4*)kk)[3] = kr[3];
        float dot = 0.f;
#pragma unroll
        for (int d = 0; d < 16; ++d) dot = fmaf(qv[d], kk[d], dot);
        dot *= 0.25f;
        float nm = fmaxf(m, dot);
        float p = __expf(dot - nm);
        float cor = __expf(m - nm);
        const float4* vr = (const float4*)(vb + ((size_t)b * N_ + n) * 64 + hd * 16);
        float vv[16];
        ((float4*)vv)[0] = vr[0]; ((float4*)vv)[1] = vr[1];
        ((float4*)vv)[2] = vr[2]; ((float4*)vv)[3] = vr[3];
        s = s * cor + p;
#pragma unroll
        for (int d = 0; d < 16; ++d) c[d] = c[d] * cor + p * vv[d];
        m = nm;
    }
#pragma unroll
    for (int o = 1; o < 64; o <<= 1) {
        float m2 = __shfl_xor(m, o);
        float s2 = __shfl_xor(s, o);
        float nm = fmaxf(m, m2);
        float w1 = __expf(m - nm), w2 = __expf(m2 - nm);
        s = s * w1 + s2 * w2;
#pragma unroll
        for (int d = 0; d < 16; ++d) {
            float c2 = __shfl_xor(c[d], o);
            c[d] = c[d] * w1 + c2 * w2;
        }
        m = nm;
    }
    __shared__ float red[4][18];
    int wv_ = threadIdx.x >> 6, lane = threadIdx.x & 63;
    if (lane == 0) {
        red[wv_][0] = m; red[wv_][1] = s;
#pragma unroll
        for (int d = 0; d < 16; ++d) red[wv_][2 + d] = c[d];
    }
    __syncthreads();
    if (threadIdx.x == 0) {
        float gm = red[0][0];
        for (int w = 1; w < 4; ++w) gm = fmaxf(gm, red[w][0]);
        float gs = 0.f, gc[16];
#pragma unroll
        for (int d = 0; d < 16; ++d) gc[d] = 0.f;
        for (int w = 0; w < 4; ++w) {
            float ww = __expf(red[w][0] - gm);
            gs += red[w][1] * ww;
#pragma unroll
            for (int d = 0; d < 16; ++d) gc[d] += red[w][2 + d] * ww;
        }
        float* p = part + (size_t)id * 18;
        p[0] = gm; p[1] = gs;
#pragma unroll
        for (int d = 0; d < 16; ++d) p[2 + d] = gc[d];
    }
}

__global__ __launch_bounds__(64) void k_comb(const float* __restrict__ part,
                                             float* __restrict__ ctx) {
    int bh = blockIdx.x, t = threadIdx.x;
    int b = bh / HEADS_, hd = bh % HEADS_;
    const float* p = part + ((size_t)bh * NCH + t) * 18;
    float m = p[0], s = p[1], c[16];
#pragma unroll
    for (int d = 0; d < 16; ++d) c[d] = p[2 + d];
    float gm = m;
#pragma unroll
    for (int o = 1; o < 64; o <<= 1) gm = fmaxf(gm, __shfl_xor(gm, o));
    float w = __expf(m - gm);
    float sw = s * w;
#pragma unroll
    for (int o = 1; o < 64; o <<= 1) sw += __shfl_xor(sw, o);
    float cg[16];
#pragma unroll
    for (int d = 0; d < 16; ++d) {
        float x = c[d] * w;
#pragma unroll
        for (int o = 1; o < 64; o <<= 1) x += __shfl_xor(x, o);
        cg[d] = x;
    }
    if (t == 0) {
#pragma unroll
        for (int d = 0; d < 16; ++d) ctx[b * 64 + hd * 16 + d] = cg[d] / sw;
    }
}

// ---------------- g = LN(a + ctx@wo + bo); wcomb = g/8 + policy_w ----------------
__global__ __launch_bounds__(64) void k_g(const float* __restrict__ a,
                                          const float* __restrict__ ctx,
                                          const float* __restrict__ wo,
                                          const float* __restrict__ bo,
                                          const float* __restrict__ lng,
                                          const float* __restrict__ lnb,
                                          const float* __restrict__ pw,
                                          float* __restrict__ wcomb) {
    int b = blockIdx.x, t = threadIdx.x;
    __shared__ float sc[64];
    sc[t] = ctx[b * 64 + t];
    __syncthreads();
    float o = bo[t];
    for (int i = 0; i < 64; ++i) o = fmaf(sc[i], wo[i * 64 + t], o);
    float y = a[b * 64 + t] + o;
    float mu = y;
#pragma unroll
    for (int oo = 1; oo < 64; oo <<= 1) mu += __shfl_xor(mu, oo);
    mu *= (1.f / 64.f);
    float d = y - mu;
    float var = d * d;
#pragma unroll
    for (int oo = 1; oo < 64; oo <<= 1) var += __shfl_xor(var, oo);
    var *= (1.f / 64.f);
    float g = d * rsqrtf(var + 1e-5f) * lng[t] + lnb[t];
    wcomb[b * 64 + t] = g * 0.125f + pw[t];
}

// ---------------- logits ----------------
__global__ __launch_bounds__(256) void k_final(const float* __restrict__ h,
                                               const float* __restrict__ wcomb,
                                               const float* __restrict__ pb,
                                               const void* __restrict__ mask,
                                               const int* __restrict__ flagp,
                                               float* __restrict__ out) {
    int idx = blockIdx.x * 256 + threadIdx.x;
    if (idx >= B_ * N_) return;
    int b = idx / N_;
    const float4* wr = (const float4*)(wcomb + b * 64);
    const float4* hr = (const float4*)(h + (size_t)idx * 64);
    float acc = pb[0];
#pragma unroll
    for (int i = 0; i < 16; ++i) {
        float4 hv = hr[i], wv = wr[i];
        acc = fmaf(hv.x, wv.x, acc);
        acc = fmaf(hv.y, wv.y, acc);
        acc = fmaf(hv.z, wv.z, acc);
        acc = fmaf(hv.w, wv.w, acc);
    }
    int flag = *flagp;
    bool mv;
    if (flag == 1)      mv = ((const int*)mask)[idx] != 0;
    else if (flag == 2) mv = ((const float*)mask)[idx] != 0.f;
    else                mv = ((const unsigned char*)mask)[idx] != 0;
    out[idx] = mv ? acc : -1.0e9f;
}

extern "C" void kernel_launch(void* const* d_in, const int* in_sizes, int n_in,
                              void* d_out, int out_size, void* d_ws, size_t ws_size,
                              hipStream_t stream) {
    const float* gn   = (const float*)d_in[0];
    const float* ad   = (const float*)d_in[1];
    const float* wnod = (const float*)d_in[2];
    const float* bnod = (const float*)d_in[3];
    const float* msgw = (const float*)d_in[4];
    const float* msgb = (const float*)d_in[5];
    const float* updw = (const float*)d_in[6];
    const float* updb = (const float*)d_in[7];
    const float* wad  = (const float*)d_in[8];
    const float* bad  = (const float*)d_in[9];
    const float* wq   = (const float*)d_in[10];
    const float* bq   = (const float*)d_in[11];
    const float* wk   = (const float*)d_in[12];
    const float* bk   = (const float*)d_in[13];
    const float* wv   = (const float*)d_in[14];
    const float* bv   = (const float*)d_in[15];
    const float* wo   = (const float*)d_in[16];
    const float* bo   = (const float*)d_in[17];
    const float* lng  = (const float*)d_in[18];
    const float* lnb  = (const float*)d_in[19];
    const float* pw   = (const float*)d_in[20];
    const float* pb   = (const float*)d_in[21];
    const int*   links= (const int*)d_in[22];
    const void*  mask = d_in[23];

    char* ws = (char*)d_ws;
    float* h    = (float*)(ws + OFF_H);
    float* bufA = (float*)(ws + OFF_A1);
    float* bufB = (float*)(ws + OFF_A2);
    int*   cnt  = (int*)(ws + OFF_CNT);
    int*   pos  = (int*)(ws + OFF_POS);
    int*   offs = (int*)(ws + OFF_OFFS);
    int*   esrc = (int*)(ws + OFF_ESRC);
    int*   edst = (int*)(ws + OFF_EDST);
    unsigned short* hb16 = (unsigned short*)(ws + OFF_HB16);
    float* avec = (float*)(ws + OFF_AVEC);
    float* qvec = (float*)(ws + OFF_Q);
    float* ctx  = (float*)(ws + OFF_CTX);
    float* wcmb = (float*)(ws + OFF_WCMB);
    int*   flag = (int*)(ws + OFF_FLAG);
    float* part = (float*)(ws + OFF_PART);
    float* out  = (float*)d_out;

    hipMemsetAsync(cnt, 0, (size_t)B_ * N_ * 4, stream);
    k_maskdetect<<<1, 1, 0, stream>>>((const unsigned int*)mask, flag);
    k_embed<<<4096, 256, 0, stream>>>(gn, wnod, bnod, h);
    int eb = (B_ * E_ + 255) / 256;
    k_count<<<eb, 256, 0, stream>>>(links, cnt);
    k_scan<<<B_, 256, 0, stream>>>(cnt, offs, pos);
    k_fill<<<eb, 256, 0, stream>>>(links, pos, esrc, edst);

    for (int l = 0; l < 2; ++l) {
        const float* mwl = msgw + (size_t)l * 128 * 64;
        const float* mbl = msgb + (size_t)l * 64;
        const float* uwl = updw + (size_t)l * 128 * 64;
        const float* ubl = updb + (size_t)l * 64;
        k_tdst<<<4096, 256, 0, stream>>>(h, mwl, mbl, bufA, hb16);
        hipMemsetAsync(bufB, 0, HB, stream);
        k_edge_mfma<<<B_ * TPB_ / 4, 256, 0, stream>>>(hb16, bufA, esrc, edst, mwl, bufB);
        k_upd<<<4096, 256, 0, stream>>>(h, bufB, uwl, ubl);
    }

    k_aq<<<B_, 64, 0, stream>>>(ad, wad, bad, wq, bq, avec, qvec);
    k_kv<<<4096, 256, 0, stream>>>(h, wk, bk, wv, bv, bufA, bufB);
    k_attn<<<B_ * HEADS_ * NCH, 256, 0, stream>>>(qvec, bufA, bufB, part);
    k_comb<<<B_ * HEADS_, 64, 0, stream>>>(part, ctx);
    k_g<<<B_, 64, 0, stream>>>(avec, ctx, wo, bo, lng, lnb, pw, wcmb);
    k_final<<<(B_ * N_ + 255) / 256, 256, 0, stream>>>(h, wcmb, pb, mask, flag, out);
}

// Round 3
// 651.374 us; speedup vs baseline: 3.7400x; 1.4894x over previous
//
#include <hip/hip_runtime.h>
#include <hip/hip_bf16.h>
#include <math.h>

// Problem constants
constexpr int B_ = 4;
constexpr int N_ = 20000;
constexpr int E_ = 320000;
constexpr int HEADS_ = 4;
constexpr int NCH = 64;                       // attention chunks per (b,head)
constexpr int CS = (N_ + NCH - 1) / NCH;      // 313
constexpr int TPB_ = E_ / 16;                 // 20000 edge tiles per batch
constexpr int NT_ = (B_ * N_) / 16;           // 5000 node tiles

typedef __attribute__((ext_vector_type(8))) short short8;   // 8 bf16
typedef __attribute__((ext_vector_type(4))) float f32x4;

// Workspace layout (bytes). ~84 MB.
constexpr size_t HB = (size_t)B_ * N_ * 64 * 4;      // 20,480,000
constexpr size_t OFF_H    = 0;
constexpr size_t OFF_A1   = HB;            // tdst, later k
constexpr size_t OFF_A2   = 2 * HB;        // agg, later v
constexpr size_t OFF_CNT  = 3 * HB;                          // B*N ints
constexpr size_t OFF_POS  = OFF_CNT + (size_t)B_ * N_ * 4;   // B*N ints
constexpr size_t OFF_OFFS = OFF_POS + (size_t)B_ * N_ * 4;   // B*(N+1) ints
constexpr size_t OFF_ESRC = OFF_OFFS + ((size_t)B_ * (N_ + 1) * 4 + 64); // B*E ints
constexpr size_t OFF_EDST = OFF_ESRC + (size_t)B_ * E_ * 4;  // B*E ints
constexpr size_t OFF_HB16 = OFF_EDST + (size_t)B_ * E_ * 4;  // B*N*64 bf16
constexpr size_t OFF_AVEC = OFF_HB16 + (size_t)B_ * N_ * 64 * 2;
constexpr size_t OFF_Q    = OFF_AVEC + 1024;
constexpr size_t OFF_CTX  = OFF_Q + 1024;
constexpr size_t OFF_WCMB = OFF_CTX + 1024;
constexpr size_t OFF_FLAG = OFF_WCMB + 1024;
constexpr size_t OFF_PART = OFF_FLAG + 64;                   // 1024*18 f partials

static __device__ __forceinline__ unsigned short f2bf(float f) {
    union { float f; unsigned u; } v; v.f = f;
    unsigned r = v.u + 0x7fffu + ((v.u >> 16) & 1u);
    return (unsigned short)(r >> 16);
}

// ---------------- mask dtype detection ----------------
__global__ void k_maskdetect(const unsigned int* __restrict__ m, int* __restrict__ flag) {
    if (blockIdx.x == 0 && threadIdx.x == 0) {
        bool alli = true, allf = true;
        for (int i = 0; i < 256; ++i) {
            unsigned v = m[i];
            alli = alli && (v <= 1u);
            allf = allf && (v == 0u || v == 0x3f800000u);
        }
        *flag = alli ? 1 : (allf ? 2 : 0);
    }
}

// ---------------- h = relu(gn @ w_node + b_node); hb16 = bf16(h) ----------------
__global__ __launch_bounds__(256) void k_embed(const float* __restrict__ gn,
                                               const float* __restrict__ w,
                                               const float* __restrict__ bias,
                                               float* __restrict__ h,
                                               unsigned short* __restrict__ hb16) {
    int lane = threadIdx.x & 63;
    float wc[16];
#pragma unroll
    for (int i = 0; i < 16; ++i) wc[i] = w[i * 64 + lane];
    float bb = bias[lane];
    int gw = (blockIdx.x * blockDim.x + threadIdx.x) >> 6;
    int nw = (gridDim.x * blockDim.x) >> 6;
    for (int node = gw; node < B_ * N_; node += nw) {
        const float* r = gn + (size_t)node * 16;
        float a0 = 0.f, a1 = 0.f, a2 = 0.f, a3 = 0.f;
#pragma unroll
        for (int i = 0; i < 16; i += 4) {
            a0 = fmaf(r[i + 0], wc[i + 0], a0);
            a1 = fmaf(r[i + 1], wc[i + 1], a1);
            a2 = fmaf(r[i + 2], wc[i + 2], a2);
            a3 = fmaf(r[i + 3], wc[i + 3], a3);
        }
        float v = fmaxf(bb + ((a0 + a1) + (a2 + a3)), 0.f);
        h[(size_t)node * 64 + lane] = v;
        hb16[(size_t)node * 64 + lane] = f2bf(v);
    }
}

// ---------------- CSR build ----------------
__global__ void k_count(const int* __restrict__ links, int* __restrict__ cnt) {
    int i = blockIdx.x * blockDim.x + threadIdx.x;
    if (i >= B_ * E_) return;
    int b = i / E_, e = i - b * E_;
    int dst = links[(size_t)b * 2 * E_ + E_ + e];
    atomicAdd(&cnt[b * N_ + dst], 1);
}

__global__ __launch_bounds__(256) void k_scan(const int* __restrict__ cnt,
                                              int* __restrict__ offs,
                                              int* __restrict__ pos) {
    __shared__ int sd[256];
    __shared__ int sbase;
    int b = blockIdx.x, t = threadIdx.x;
    if (t == 0) { sbase = 0; offs[(size_t)b * (N_ + 1)] = 0; }
    __syncthreads();
    for (int base = 0; base < N_; base += 256) {
        int idx = base + t;
        int c = (idx < N_) ? cnt[(size_t)b * N_ + idx] : 0;
        sd[t] = c;
        __syncthreads();
        for (int ofs = 1; ofs < 256; ofs <<= 1) {
            int v = (t >= ofs) ? sd[t - ofs] : 0;
            __syncthreads();
            sd[t] += v;
            __syncthreads();
        }
        int incl = sd[t];
        int run = sbase;
        __syncthreads();
        if (idx < N_) {
            offs[(size_t)b * (N_ + 1) + idx + 1] = run + incl;
            pos[(size_t)b * N_ + idx] = run + incl - c;
        }
        if (t == 255) sbase = run + incl;
        __syncthreads();
    }
}

__global__ void k_fill(const int* __restrict__ links, int* __restrict__ pos,
                       int* __restrict__ esrc, int* __restrict__ edst) {
    int i = blockIdx.x * blockDim.x + threadIdx.x;
    if (i >= B_ * E_) return;
    int b = i / E_, e = i - b * E_;
    int src = links[(size_t)b * 2 * E_ + e];
    int dst = links[(size_t)b * 2 * E_ + E_ + e];
    int slot = atomicAdd(&pos[b * N_ + dst], 1);
    esrc[(size_t)b * E_ + slot] = src;
    edst[(size_t)b * E_ + slot] = dst;
}

// ---------------- tdst = W2^T h + msg_b (MFMA node GEMM) ----------------
__global__ __launch_bounds__(256) void k_tdst_mfma(const unsigned short* __restrict__ hb16,
                                                   const float* __restrict__ mw,
                                                   const float* __restrict__ mb,
                                                   float* __restrict__ td) {
    int lane = threadIdx.x & 63;
    int g = lane >> 4, c = lane & 15;
    short8 bf[4][2];
#pragma unroll
    for (int nt = 0; nt < 4; ++nt)
#pragma unroll
        for (int ks = 0; ks < 2; ++ks)
#pragma unroll
            for (int j = 0; j < 8; ++j)
                bf[nt][ks][j] = (short)f2bf(mw[(64 + ks * 32 + g * 8 + j) * 64 + nt * 16 + c]);
    float mbv[4];
#pragma unroll
    for (int nt = 0; nt < 4; ++nt) mbv[nt] = mb[nt * 16 + c];

    int wid = blockIdx.x * 4 + (threadIdx.x >> 6);
    int nw = gridDim.x * 4;
    f32x4 zero = {0.f, 0.f, 0.f, 0.f};
    for (int t = wid; t < NT_; t += nw) {
        const unsigned short* ap = hb16 + ((size_t)t * 16 + c) * 64;
        short8 a0 = *(const short8*)(ap + g * 8);
        short8 a1 = *(const short8*)(ap + 32 + g * 8);
        f32x4 acc[4];
#pragma unroll
        for (int nt = 0; nt < 4; ++nt) {
            acc[nt] = __builtin_amdgcn_mfma_f32_16x16x32_bf16(a0, bf[nt][0], zero, 0, 0, 0);
            acc[nt] = __builtin_amdgcn_mfma_f32_16x16x32_bf16(a1, bf[nt][1], acc[nt], 0, 0, 0);
        }
#pragma unroll
        for (int r = 0; r < 4; ++r) {
            size_t row = (size_t)t * 16 + 4 * g + r;
#pragma unroll
            for (int nt = 0; nt < 4; ++nt)
                td[row * 64 + nt * 16 + c] = acc[nt][r] + mbv[nt];
        }
    }
}

// ---------------- fused MFMA edge kernel (grid-stride, hoisted W1) ----------------
__global__ __launch_bounds__(256) void k_edge_mfma(const unsigned short* __restrict__ hb16,
                                                   const float* __restrict__ td,
                                                   const int* __restrict__ esrc,
                                                   const int* __restrict__ edst,
                                                   const float* __restrict__ mw,
                                                   float* __restrict__ agg) {
    int lane = threadIdx.x & 63;
    int g = lane >> 4, c = lane & 15;
    short8 bf[4][2];
#pragma unroll
    for (int nt = 0; nt < 4; ++nt)
#pragma unroll
        for (int ks = 0; ks < 2; ++ks)
#pragma unroll
            for (int j = 0; j < 8; ++j)
                bf[nt][ks][j] = (short)f2bf(mw[(ks * 32 + g * 8 + j) * 64 + nt * 16 + c]);

    int wid = blockIdx.x * 4 + (threadIdx.x >> 6);
    int nw = gridDim.x * 4;
    f32x4 zero = {0.f, 0.f, 0.f, 0.f};
    for (int wgl = wid; wgl < B_ * TPB_; wgl += nw) {
        int b = wgl / TPB_;
        int t0 = wgl - b * TPB_;
        int s0 = t0 * 16;
        const int* ep = esrc + (size_t)b * E_;
        const int* dp = edst + (size_t)b * E_;

        int src = ep[s0 + c];
        const unsigned short* hrow = hb16 + ((size_t)(b * N_) + src) * 64;
        short8 a0 = *(const short8*)(hrow + g * 8);
        short8 a1 = *(const short8*)(hrow + 32 + g * 8);

        f32x4 acc[4];
#pragma unroll
        for (int nt = 0; nt < 4; ++nt) {
            acc[nt] = __builtin_amdgcn_mfma_f32_16x16x32_bf16(a0, bf[nt][0], zero, 0, 0, 0);
            acc[nt] = __builtin_amdgcn_mfma_f32_16x16x32_bf16(a1, bf[nt][1], acc[nt], 0, 0, 0);
        }

        int myd[4];
#pragma unroll
        for (int r = 0; r < 4; ++r) myd[r] = dp[s0 + 4 * g + r];
        float val[4][4]; // [nt][r]
#pragma unroll
        for (int r = 0; r < 4; ++r) {
            const float* trow = td + ((size_t)(b * N_) + myd[r]) * 64;
#pragma unroll
            for (int nt = 0; nt < 4; ++nt)
                val[nt][r] = fmaxf(acc[nt][r] + trow[nt * 16 + c], 0.f);
        }

        int i = 0;
        while (i < 16) {
            int d = dp[s0 + i];
            int j = i + 1;
            while (j < 16 && dp[s0 + j] == d) ++j;
            float s0v = 0.f, s1v = 0.f, s2v = 0.f, s3v = 0.f;
#pragma unroll
            for (int r = 0; r < 4; ++r) {
                int rr = 4 * g + r;
                bool in = (rr >= i) && (rr < j);
                s0v += in ? val[0][r] : 0.f;
                s1v += in ? val[1][r] : 0.f;
                s2v += in ? val[2][r] : 0.f;
                s3v += in ? val[3][r] : 0.f;
            }
            s0v += __shfl_xor(s0v, 16); s0v += __shfl_xor(s0v, 32);
            s1v += __shfl_xor(s1v, 16); s1v += __shfl_xor(s1v, 32);
            s2v += __shfl_xor(s2v, 16); s2v += __shfl_xor(s2v, 32);
            s3v += __shfl_xor(s3v, 16); s3v += __shfl_xor(s3v, 32);
            float outv = (g == 0) ? s0v : (g == 1) ? s1v : (g == 2) ? s2v : s3v;
            atomicAdd(&agg[((size_t)(b * N_) + d) * 64 + g * 16 + c], outv);
            i = j;
        }
    }
}

// ---------------- h += relu([h,agg] @ upd_w + upd_b) (MFMA) ----------------
__global__ __launch_bounds__(256) void k_upd_mfma(float* __restrict__ h,
                                                  unsigned short* __restrict__ hb16,
                                                  const float* __restrict__ agg,
                                                  const float* __restrict__ uw,
                                                  const float* __restrict__ ub) {
    int lane = threadIdx.x & 63;
    int g = lane >> 4, c = lane & 15;
    short8 bh[4][2], ba[4][2];
#pragma unroll
    for (int nt = 0; nt < 4; ++nt)
#pragma unroll
        for (int ks = 0; ks < 2; ++ks)
#pragma unroll
            for (int j = 0; j < 8; ++j) {
                bh[nt][ks][j] = (short)f2bf(uw[(ks * 32 + g * 8 + j) * 64 + nt * 16 + c]);
                ba[nt][ks][j] = (short)f2bf(uw[(64 + ks * 32 + g * 8 + j) * 64 + nt * 16 + c]);
            }
    float ubv[4];
#pragma unroll
    for (int nt = 0; nt < 4; ++nt) ubv[nt] = ub[nt * 16 + c];

    int wid = blockIdx.x * 4 + (threadIdx.x >> 6);
    int nw = gridDim.x * 4;
    f32x4 zero = {0.f, 0.f, 0.f, 0.f};
    for (int t = wid; t < NT_; t += nw) {
        const unsigned short* ap = hb16 + ((size_t)t * 16 + c) * 64;
        short8 a0 = *(const short8*)(ap + g * 8);
        short8 a1 = *(const short8*)(ap + 32 + g * 8);

        const float* gp = agg + ((size_t)t * 16 + c) * 64;
        float4 q0 = *(const float4*)(gp + g * 8);
        float4 q1 = *(const float4*)(gp + g * 8 + 4);
        float4 q2 = *(const float4*)(gp + 32 + g * 8);
        float4 q3 = *(const float4*)(gp + 32 + g * 8 + 4);
        short8 s0, s1;
        s0[0] = (short)f2bf(q0.x); s0[1] = (short)f2bf(q0.y);
        s0[2] = (short)f2bf(q0.z); s0[3] = (short)f2bf(q0.w);
        s0[4] = (short)f2bf(q1.x); s0[5] = (short)f2bf(q1.y);
        s0[6] = (short)f2bf(q1.z); s0[7] = (short)f2bf(q1.w);
        s1[0] = (short)f2bf(q2.x); s1[1] = (short)f2bf(q2.y);
        s1[2] = (short)f2bf(q2.z); s1[3] = (short)f2bf(q2.w);
        s1[4] = (short)f2bf(q3.x); s1[5] = (short)f2bf(q3.y);
        s1[6] = (short)f2bf(q3.z); s1[7] = (short)f2bf(q3.w);

        f32x4 acc[4];
#pragma unroll
        for (int nt = 0; nt < 4; ++nt) {
            acc[nt] = __builtin_amdgcn_mfma_f32_16x16x32_bf16(a0, bh[nt][0], zero, 0, 0, 0);
            acc[nt] = __builtin_amdgcn_mfma_f32_16x16x32_bf16(a1, bh[nt][1], acc[nt], 0, 0, 0);
            acc[nt] = __builtin_amdgcn_mfma_f32_16x16x32_bf16(s0, ba[nt][0], acc[nt], 0, 0, 0);
            acc[nt] = __builtin_amdgcn_mfma_f32_16x16x32_bf16(s1, ba[nt][1], acc[nt], 0, 0, 0);
        }
#pragma unroll
        for (int r = 0; r < 4; ++r) {
            size_t row = (size_t)t * 16 + 4 * g + r;
#pragma unroll
            for (int nt = 0; nt < 4; ++nt) {
                size_t idx = row * 64 + nt * 16 + c;
                float v = h[idx] + fmaxf(acc[nt][r] + ubv[nt], 0.f);
                h[idx] = v;
                hb16[idx] = f2bf(v);
            }
        }
    }
}

// ---------------- k/v projections (MFMA) ----------------
__global__ __launch_bounds__(256) void k_kv_mfma(const unsigned short* __restrict__ hb16,
                                                 const float* __restrict__ wk,
                                                 const float* __restrict__ bk,
                                                 const float* __restrict__ wv,
                                                 const float* __restrict__ bv,
                                                 float* __restrict__ kb,
                                                 float* __restrict__ vb) {
    int lane = threadIdx.x & 63;
    int g = lane >> 4, c = lane & 15;
    short8 bkf[4][2], bvf[4][2];
#pragma unroll
    for (int nt = 0; nt < 4; ++nt)
#pragma unroll
        for (int ks = 0; ks < 2; ++ks)
#pragma unroll
            for (int j = 0; j < 8; ++j) {
                bkf[nt][ks][j] = (short)f2bf(wk[(ks * 32 + g * 8 + j) * 64 + nt * 16 + c]);
                bvf[nt][ks][j] = (short)f2bf(wv[(ks * 32 + g * 8 + j) * 64 + nt * 16 + c]);
            }
    float bkv[4], bvv[4];
#pragma unroll
    for (int nt = 0; nt < 4; ++nt) { bkv[nt] = bk[nt * 16 + c]; bvv[nt] = bv[nt * 16 + c]; }

    int wid = blockIdx.x * 4 + (threadIdx.x >> 6);
    int nw = gridDim.x * 4;
    f32x4 zero = {0.f, 0.f, 0.f, 0.f};
    for (int t = wid; t < NT_; t += nw) {
        const unsigned short* ap = hb16 + ((size_t)t * 16 + c) * 64;
        short8 a0 = *(const short8*)(ap + g * 8);
        short8 a1 = *(const short8*)(ap + 32 + g * 8);
        f32x4 ak[4], av[4];
#pragma unroll
        for (int nt = 0; nt < 4; ++nt) {
            ak[nt] = __builtin_amdgcn_mfma_f32_16x16x32_bf16(a0, bkf[nt][0], zero, 0, 0, 0);
            ak[nt] = __builtin_amdgcn_mfma_f32_16x16x32_bf16(a1, bkf[nt][1], ak[nt], 0, 0, 0);
            av[nt] = __builtin_amdgcn_mfma_f32_16x16x32_bf16(a0, bvf[nt][0], zero, 0, 0, 0);
            av[nt] = __builtin_amdgcn_mfma_f32_16x16x32_bf16(a1, bvf[nt][1], av[nt], 0, 0, 0);
        }
#pragma unroll
        for (int r = 0; r < 4; ++r) {
            size_t row = (size_t)t * 16 + 4 * g + r;
#pragma unroll
            for (int nt = 0; nt < 4; ++nt) {
                kb[row * 64 + nt * 16 + c] = ak[nt][r] + bkv[nt];
                vb[row * 64 + nt * 16 + c] = av[nt][r] + bvv[nt];
            }
        }
    }
}

// ---------------- a = relu(ad @ w_ad + b_ad); q = a @ wq + bq ----------------
__global__ __launch_bounds__(64) void k_aq(const float* __restrict__ ad,
                                           const float* __restrict__ wad,
                                           const float* __restrict__ bad,
                                           const float* __restrict__ wq,
                                           const float* __restrict__ bq,
                                           float* __restrict__ a_out,
                                           float* __restrict__ q_out) {
    int b = blockIdx.x, t = threadIdx.x;
    __shared__ float sa[64];
    float acc = bad[t];
#pragma unroll
    for (int i = 0; i < 8; ++i) acc = fmaf(ad[b * 8 + i], wad[i * 64 + t], acc);
    float av = fmaxf(acc, 0.f);
    sa[t] = av;
    a_out[b * 64 + t] = av;
    __syncthreads();
    float qa = bq[t];
    for (int i = 0; i < 64; ++i) qa = fmaf(sa[i], wq[i * 64 + t], qa);
    q_out[b * 64 + t] = qa;
}

// ---------------- attention: chunked online softmax partials ----------------
__global__ __launch_bounds__(256) void k_attn(const float* __restrict__ q,
                                              const float* __restrict__ kb,
                                              const float* __restrict__ vb,
                                              float* __restrict__ part) {
    int id = blockIdx.x;
    int ch = id % NCH;
    int bh = id / NCH;
    int b = bh / HEADS_, hd = bh % HEADS_;
    float qv[16];
#pragma unroll
    for (int d = 0; d < 16; ++d) qv[d] = q[b * 64 + hd * 16 + d];
    float m = -1e30f, s = 0.f, c[16];
#pragma unroll
    for (int d = 0; d < 16; ++d) c[d] = 0.f;
    int n0 = ch * CS;
    int n1 = n0 + CS; if (n1 > N_) n1 = N_;
    for (int n = n0 + threadIdx.x; n < n1; n += 256) {
        const float4* kr = (const float4*)(kb + ((size_t)b * N_ + n) * 64 + hd * 16);
        float kk[16];
        ((float4*)kk)[0] = kr[0]; ((float4*)kk)[1] = kr[1];
        ((float4*)kk)[2] = kr[2]; ((float4*)kk)[3] = kr[3];
        float dot = 0.f;
#pragma unroll
        for (int d = 0; d < 16; ++d) dot = fmaf(qv[d], kk[d], dot);
        dot *= 0.25f;
        float nm = fmaxf(m, dot);
        float p = __expf(dot - nm);
        float cor = __expf(m - nm);
        const float4* vr = (const float4*)(vb + ((size_t)b * N_ + n) * 64 + hd * 16);
        float vv[16];
        ((float4*)vv)[0] = vr[0]; ((float4*)vv)[1] = vr[1];
        ((float4*)vv)[2] = vr[2]; ((float4*)vv)[3] = vr[3];
        s = s * cor + p;
#pragma unroll
        for (int d = 0; d < 16; ++d) c[d] = c[d] * cor + p * vv[d];
        m = nm;
    }
#pragma unroll
    for (int o = 1; o < 64; o <<= 1) {
        float m2 = __shfl_xor(m, o);
        float s2 = __shfl_xor(s, o);
        float nm = fmaxf(m, m2);
        float w1 = __expf(m - nm), w2 = __expf(m2 - nm);
        s = s * w1 + s2 * w2;
#pragma unroll
        for (int d = 0; d < 16; ++d) {
            float c2 = __shfl_xor(c[d], o);
            c[d] = c[d] * w1 + c2 * w2;
        }
        m = nm;
    }
    __shared__ float red[4][18];
    int wv_ = threadIdx.x >> 6, lane = threadIdx.x & 63;
    if (lane == 0) {
        red[wv_][0] = m; red[wv_][1] = s;
#pragma unroll
        for (int d = 0; d < 16; ++d) red[wv_][2 + d] = c[d];
    }
    __syncthreads();
    if (threadIdx.x == 0) {
        float gm = red[0][0];
        for (int w = 1; w < 4; ++w) gm = fmaxf(gm, red[w][0]);
        float gs = 0.f, gc[16];
#pragma unroll
        for (int d = 0; d < 16; ++d) gc[d] = 0.f;
        for (int w = 0; w < 4; ++w) {
            float ww = __expf(red[w][0] - gm);
            gs += red[w][1] * ww;
#pragma unroll
            for (int d = 0; d < 16; ++d) gc[d] += red[w][2 + d] * ww;
        }
        float* p = part + (size_t)id * 18;
        p[0] = gm; p[1] = gs;
#pragma unroll
        for (int d = 0; d < 16; ++d) p[2 + d] = gc[d];
    }
}

__global__ __launch_bounds__(64) void k_comb(const float* __restrict__ part,
                                             float* __restrict__ ctx) {
    int bh = blockIdx.x, t = threadIdx.x;
    int b = bh / HEADS_, hd = bh % HEADS_;
    const float* p = part + ((size_t)bh * NCH + t) * 18;
    float m = p[0], s = p[1], c[16];
#pragma unroll
    for (int d = 0; d < 16; ++d) c[d] = p[2 + d];
    float gm = m;
#pragma unroll
    for (int o = 1; o < 64; o <<= 1) gm = fmaxf(gm, __shfl_xor(gm, o));
    float w = __expf(m - gm);
    float sw = s * w;
#pragma unroll
    for (int o = 1; o < 64; o <<= 1) sw += __shfl_xor(sw, o);
    float cg[16];
#pragma unroll
    for (int d = 0; d < 16; ++d) {
        float x = c[d] * w;
#pragma unroll
        for (int o = 1; o < 64; o <<= 1) x += __shfl_xor(x, o);
        cg[d] = x;
    }
    if (t == 0) {
#pragma unroll
        for (int d = 0; d < 16; ++d) ctx[b * 64 + hd * 16 + d] = cg[d] / sw;
    }
}

// ---------------- g = LN(a + ctx@wo + bo); wcomb = g/8 + policy_w ----------------
__global__ __launch_bounds__(64) void k_g(const float* __restrict__ a,
                                          const float* __restrict__ ctx,
                                          const float* __restrict__ wo,
                                          const float* __restrict__ bo,
                                          const float* __restrict__ lng,
                                          const float* __restrict__ lnb,
                                          const float* __restrict__ pw,
                                          float* __restrict__ wcomb) {
    int b = blockIdx.x, t = threadIdx.x;
    __shared__ float sc[64];
    sc[t] = ctx[b * 64 + t];
    __syncthreads();
    float o = bo[t];
    for (int i = 0; i < 64; ++i) o = fmaf(sc[i], wo[i * 64 + t], o);
    float y = a[b * 64 + t] + o;
    float mu = y;
#pragma unroll
    for (int oo = 1; oo < 64; oo <<= 1) mu += __shfl_xor(mu, oo);
    mu *= (1.f / 64.f);
    float d = y - mu;
    float var = d * d;
#pragma unroll
    for (int oo = 1; oo < 64; oo <<= 1) var += __shfl_xor(var, oo);
    var *= (1.f / 64.f);
    float g = d * rsqrtf(var + 1e-5f) * lng[t] + lnb[t];
    wcomb[b * 64 + t] = g * 0.125f + pw[t];
}

// ---------------- logits ----------------
__global__ __launch_bounds__(256) void k_final(const float* __restrict__ h,
                                               const float* __restrict__ wcomb,
                                               const float* __restrict__ pb,
                                               const void* __restrict__ mask,
                                               const int* __restrict__ flagp,
                                               float* __restrict__ out) {
    int idx = blockIdx.x * 256 + threadIdx.x;
    if (idx >= B_ * N_) return;
    int b = idx / N_;
    const float4* wr = (const float4*)(wcomb + b * 64);
    const float4* hr = (const float4*)(h + (size_t)idx * 64);
    float acc = pb[0];
#pragma unroll
    for (int i = 0; i < 16; ++i) {
        float4 hv = hr[i], wv = wr[i];
        acc = fmaf(hv.x, wv.x, acc);
        acc = fmaf(hv.y, wv.y, acc);
        acc = fmaf(hv.z, wv.z, acc);
        acc = fmaf(hv.w, wv.w, acc);
    }
    int flag = *flagp;
    bool mv;
    if (flag == 1)      mv = ((const int*)mask)[idx] != 0;
    else if (flag == 2) mv = ((const float*)mask)[idx] != 0.f;
    else                mv = ((const unsigned char*)mask)[idx] != 0;
    out[idx] = mv ? acc : -1.0e9f;
}

extern "C" void kernel_launch(void* const* d_in, const int* in_sizes, int n_in,
                              void* d_out, int out_size, void* d_ws, size_t ws_size,
                              hipStream_t stream) {
    const float* gn   = (const float*)d_in[0];
    const float* ad   = (const float*)d_in[1];
    const float* wnod = (const float*)d_in[2];
    const float* bnod = (const float*)d_in[3];
    const float* msgw = (const float*)d_in[4];
    const float* msgb = (const float*)d_in[5];
    const float* updw = (const float*)d_in[6];
    const float* updb = (const float*)d_in[7];
    const float* wad  = (const float*)d_in[8];
    const float* bad  = (const float*)d_in[9];
    const float* wq   = (const float*)d_in[10];
    const float* bq   = (const float*)d_in[11];
    const float* wk   = (const float*)d_in[12];
    const float* bk   = (const float*)d_in[13];
    const float* wv   = (const float*)d_in[14];
    const float* bv   = (const float*)d_in[15];
    const float* wo   = (const float*)d_in[16];
    const float* bo   = (const float*)d_in[17];
    const float* lng  = (const float*)d_in[18];
    const float* lnb  = (const float*)d_in[19];
    const float* pw   = (const float*)d_in[20];
    const float* pb   = (const float*)d_in[21];
    const int*   links= (const int*)d_in[22];
    const void*  mask = d_in[23];

    char* ws = (char*)d_ws;
    float* h    = (float*)(ws + OFF_H);
    float* bufA = (float*)(ws + OFF_A1);
    float* bufB = (float*)(ws + OFF_A2);
    int*   cnt  = (int*)(ws + OFF_CNT);
    int*   pos  = (int*)(ws + OFF_POS);
    int*   offs = (int*)(ws + OFF_OFFS);
    int*   esrc = (int*)(ws + OFF_ESRC);
    int*   edst = (int*)(ws + OFF_EDST);
    unsigned short* hb16 = (unsigned short*)(ws + OFF_HB16);
    float* avec = (float*)(ws + OFF_AVEC);
    float* qvec = (float*)(ws + OFF_Q);
    float* ctx  = (float*)(ws + OFF_CTX);
    float* wcmb = (float*)(ws + OFF_WCMB);
    int*   flag = (int*)(ws + OFF_FLAG);
    float* part = (float*)(ws + OFF_PART);
    float* out  = (float*)d_out;

    hipMemsetAsync(cnt, 0, (size_t)B_ * N_ * 4, stream);
    k_maskdetect<<<1, 1, 0, stream>>>((const unsigned int*)mask, flag);
    k_embed<<<4096, 256, 0, stream>>>(gn, wnod, bnod, h, hb16);
    int eb = (B_ * E_ + 255) / 256;
    k_count<<<eb, 256, 0, stream>>>(links, cnt);
    k_scan<<<B_, 256, 0, stream>>>(cnt, offs, pos);
    k_fill<<<eb, 256, 0, stream>>>(links, pos, esrc, edst);

    for (int l = 0; l < 2; ++l) {
        const float* mwl = msgw + (size_t)l * 128 * 64;
        const float* mbl = msgb + (size_t)l * 64;
        const float* uwl = updw + (size_t)l * 128 * 64;
        const float* ubl = updb + (size_t)l * 64;
        k_tdst_mfma<<<512, 256, 0, stream>>>(hb16, mwl, mbl, bufA);
        hipMemsetAsync(bufB, 0, HB, stream);
        k_edge_mfma<<<2048, 256, 0, stream>>>(hb16, bufA, esrc, edst, mwl, bufB);
        k_upd_mfma<<<512, 256, 0, stream>>>(h, hb16, bufB, uwl, ubl);
    }

    k_aq<<<B_, 64, 0, stream>>>(ad, wad, bad, wq, bq, avec, qvec);
    k_kv_mfma<<<512, 256, 0, stream>>>(hb16, wk, bk, wv, bv, bufA, bufB);
    k_attn<<<B_ * HEADS_ * NCH, 256, 0, stream>>>(qvec, bufA, bufB, part);
    k_comb<<<B_ * HEADS_, 64, 0, stream>>>(part, ctx);
    k_g<<<B_, 64, 0, stream>>>(avec, ctx, wo, bo, lng, lnb, pw, wcmb);
    k_final<<<(B_ * N_ + 255) / 256, 256, 0, stream>>>(h, wcmb, pb, mask, flag, out);
}